// Round 6
// baseline (320.033 us; speedup 1.0000x reference)
//
#include <hip/hip_runtime.h>
#include <math.h>

#define BB 4
#define LL 2048
#define DD 1024
#define HH 16
#define HD 64
#define BL (BB*LL)

typedef __attribute__((ext_vector_type(8))) short bf16x8;
typedef __attribute__((ext_vector_type(4))) short bf16x4;
typedef __attribute__((ext_vector_type(4))) float f32x4;

__device__ inline short f2bf(float f) {
    union { float f; unsigned u; } v; v.f = f;
    unsigned r = v.u + 0x7fffu + ((v.u >> 16) & 1u);   // RNE
    return (short)(r >> 16);
}

// pack two fp32 -> two bf16 (truncation; p>=0 so bias is benign, ~2^-9 rel)
__device__ inline unsigned pk_bf16(float a, float b) {
    union { float f; unsigned u; } x, y; x.f = a; y.f = b;
    return (x.u >> 16) | (y.u & 0xffff0000u);
}

__device__ inline float exp2x(float x) {
#if __has_builtin(__builtin_amdgcn_exp2f)
    return __builtin_amdgcn_exp2f(x);
#else
    return exp2f(x);
#endif
}

__device__ inline f32x4 mfma16x16x16_bf16(bf16x4 a, bf16x4 b, f32x4 c) {
#if __has_builtin(__builtin_amdgcn_mfma_f32_16x16x16bf16_1k)
    return __builtin_amdgcn_mfma_f32_16x16x16bf16_1k(a, b, c, 0, 0, 0);
#elif __has_builtin(__builtin_amdgcn_mfma_f32_16x16x16_bf16)
    return __builtin_amdgcn_mfma_f32_16x16x16_bf16(a, b, c, 0, 0, 0);
#else
    f32x4 d;
    asm volatile("v_mfma_f32_16x16x16_bf16 %0, %1, %2, %3"
                 : "=v"(d) : "v"(a), "v"(b), "v"(c));
    return d;
#endif
}

// ---------------------------------------------------------------------------
// fp32 -> bf16 cast, 8 elem/thread. n must be a multiple of 2048.
// ---------------------------------------------------------------------------
__global__ __launch_bounds__(256) void cast_kernel(
    const float* __restrict__ in, short* __restrict__ out, int n)
{
    int i = (blockIdx.x * 256 + threadIdx.x) * 8;
    float4 a = *(const float4*)(in + i);
    float4 b = *(const float4*)(in + i + 4);
    bf16x8 o;
    o[0]=f2bf(a.x); o[1]=f2bf(a.y); o[2]=f2bf(a.z); o[3]=f2bf(a.w);
    o[4]=f2bf(b.x); o[5]=f2bf(b.y); o[6]=f2bf(b.z); o[7]=f2bf(b.w);
    *(bf16x8*)(out + i) = o;
}

// ---------------------------------------------------------------------------
// RoPE table: tab[l*32 + f] = (cos, sin) of l * 10000^(-f/32), f=0..31.
// 65536 entries = 512 KB, L2/L3-resident. grid 256 x 256.
// ---------------------------------------------------------------------------
__global__ __launch_bounds__(256) void rope_tab_kernel(float2* __restrict__ tab)
{
    int idx = blockIdx.x * 256 + threadIdx.x;
    int lq = idx >> 5, f = idx & 31;
    float inv = __expf((float)f * (-9.210340371976184f / 32.0f));
    float s, c;
    sincosf((float)lq * inv, &s, &c);
    tab[idx] = make_float2(c, s);
}

// ---------------------------------------------------------------------------
// Shared 128x128-tile bf16 MFMA K-loop, software-pipelined register staging:
// next K-tile is loaded to regs BEFORE computing the current one, so the
// vmcnt wait at ds_write is covered by the compute phase (R5: latency was
// fully exposed at the barrier every iter).
// ---------------------------------------------------------------------------
__device__ inline void gemm_bt_128(const short* __restrict__ A,
                                   const short* __restrict__ B,
                                   short* Ash, short* Bsh,
                                   int i0, int n0, f32x4 (&acc)[4][4])
{
    const int t  = threadIdx.x;
    const int w  = t >> 6;
    const int l  = t & 63;
    const int g  = (t >> 4) & 3;
    const int ln = t & 15;
    const int rh = (w >> 1) * 64;
    const int ch = (w & 1) * 64;
    const int srow = w * 8 + (l >> 3);     // 0..31 within 32-row group
    const int skol = (l & 7) * 8;          // 0..56

    const short* ga = A + (size_t)(i0 + srow) * DD + skol;
    const short* gb = B + (size_t)(n0 + srow) * DD + skol;

    bf16x8 ra[4], rb[4];
    #pragma unroll
    for (int j = 0; j < 4; ++j) {
        ra[j] = *(const bf16x8*)(ga + (size_t)j * 32 * DD);
        rb[j] = *(const bf16x8*)(gb + (size_t)j * 32 * DD);
    }

    for (int k0 = 0; k0 < DD; k0 += 64) {
        __syncthreads();   // previous tile fully consumed
        #pragma unroll
        for (int j = 0; j < 4; ++j) {
            *(bf16x8*)(Ash + (srow + j*32)*64 + skol) = ra[j];
            *(bf16x8*)(Bsh + (srow + j*32)*64 + skol) = rb[j];
        }
        __syncthreads();

        // prefetch next tile (branchless wrap keeps loads in-bounds)
        int kn = (k0 + 64) & (DD - 1);
        #pragma unroll
        for (int j = 0; j < 4; ++j) {
            ra[j] = *(const bf16x8*)(ga + kn + (size_t)j * 32 * DD);
            rb[j] = *(const bf16x8*)(gb + kn + (size_t)j * 32 * DD);
        }

        #pragma unroll
        for (int kk = 0; kk < 2; ++kk) {
            bf16x8 af[4], bfr[4];
            #pragma unroll
            for (int mi = 0; mi < 4; ++mi)
                af[mi] = *(const bf16x8*)(Ash + (rh + mi*16 + ln)*64 + kk*32 + 8*g);
            #pragma unroll
            for (int nj = 0; nj < 4; ++nj)
                bfr[nj] = *(const bf16x8*)(Bsh + (ch + nj*16 + ln)*64 + kk*32 + 8*g);
            #pragma unroll
            for (int mi = 0; mi < 4; ++mi)
                #pragma unroll
                for (int nj = 0; nj < 4; ++nj)
                    acc[mi][nj] = __builtin_amdgcn_mfma_f32_16x16x32_bf16(
                        af[mi], bfr[nj], acc[mi][nj], 0, 0, 0);
        }
    }
}

// ---------------------------------------------------------------------------
// Kernel 1: QKV projection + RoPE. grid (DD/128, BL/128, 3).
// z=0/1: Q/K roped via precomputed cos/sin table (R5 burned ~32 sincosf per
// thread here); Q scaled by 0.125*log2(e). z=2: V written transposed
// (B,H,Hd,L) via two-pass LDS transpose (buf[64][136] fits in Ash+Bsh).
// ---------------------------------------------------------------------------
__global__ __launch_bounds__(256) void qkv_mfma_kernel(
    const short* __restrict__ xb, const short* __restrict__ Wqb,
    const short* __restrict__ Wkb, const short* __restrict__ Wvb,
    const float2* __restrict__ rope_tab,
    short* __restrict__ Qo, short* __restrict__ Ko, short* __restrict__ Vo)
{
    __shared__ short Ash[128*64];
    __shared__ short Bsh[128*64];

    const int z  = blockIdx.z;
    const short* Wm = (z == 0) ? Wqb : ((z == 1) ? Wkb : Wvb);
    const int i0 = blockIdx.y * 128;
    const int n0 = blockIdx.x * 128;

    f32x4 acc[4][4];
    #pragma unroll
    for (int mi = 0; mi < 4; ++mi)
        #pragma unroll
        for (int nj = 0; nj < 4; ++nj) acc[mi][nj] = (f32x4){0.f,0.f,0.f,0.f};

    gemm_bt_128(xb, Wm, Ash, Bsh, i0, n0, acc);

    const int t  = threadIdx.x;
    const int w  = t >> 6;
    const int g  = (t >> 4) & 3;
    const int ln = t & 15;
    const int rh = (w >> 1) * 64;

    if (z == 2) {
        // two passes over heads; buf[64 d][136 seq-stride] spans Ash..Bsh.
        short* buf = Ash;
        const int b = i0 >> 11, l0 = i0 & (LL - 1);
        const int d = t >> 2;
        const int c = t & 3;
        #pragma unroll
        for (int hp = 0; hp < 2; ++hp) {
            __syncthreads();
            if ((w & 1) == hp) {
                #pragma unroll
                for (int nj = 0; nj < 4; ++nj)
                    #pragma unroll
                    for (int mi = 0; mi < 4; ++mi)
                        #pragma unroll
                        for (int r = 0; r < 4; ++r)
                            buf[(nj*16 + ln)*136 + rh + mi*16 + 4*g + r]
                                = f2bf(acc[mi][nj][r]);
            }
            __syncthreads();
            short* dst = Vo + ((size_t)((b*HH + blockIdx.x*2 + hp)*HD + d)) * LL + l0;
            #pragma unroll
            for (int j = 0; j < 4; ++j)
                *(bf16x8*)(dst + c*8 + j*32) =
                    *(const bf16x8*)(buf + d*136 + c*8 + j*32);
        }
    } else {
        const int h = blockIdx.x * 2 + (w & 1);
        short* Om = (z == 0) ? Qo : Ko;
        // Q: 1/sqrt(64) * log2(e) so scores feed exp2 directly
        const float sc = (z == 0) ? 0.180336880111112f : 1.0f;
        #pragma unroll
        for (int mi = 0; mi < 4; ++mi)
            #pragma unroll
            for (int r = 0; r < 4; ++r) {
                int i = i0 + rh + mi*16 + 4*g + r;
                int b = i >> 11, lq = i & (LL - 1);
                float2 cs0 = rope_tab[lq*32 + ln];        // freq ln
                float2 cs1 = rope_tab[lq*32 + ln + 16];   // freq ln+16
                float r0 = (acc[mi][0][r]*cs0.x - acc[mi][2][r]*cs0.y) * sc;
                float r2 = (acc[mi][2][r]*cs0.x + acc[mi][0][r]*cs0.y) * sc;
                float r1 = (acc[mi][1][r]*cs1.x - acc[mi][3][r]*cs1.y) * sc;
                float r3 = (acc[mi][3][r]*cs1.x + acc[mi][1][r]*cs1.y) * sc;
                size_t base = ((size_t)(b*HH + h) * LL + lq) * HD;
                Om[base + ln     ] = f2bf(r0);
                Om[base + ln + 16] = f2bf(r1);
                Om[base + ln + 32] = f2bf(r2);
                Om[base + ln + 48] = f2bf(r3);
            }
    }
}

// ---------------------------------------------------------------------------
// Kernel 2: bf16 MFMA flash attention, no-max softmax, register-resident P,
// software-pipelined K/V staging. grid = (L/128, B*H), block = 256.
// ---------------------------------------------------------------------------
__global__ __launch_bounds__(256) void attn_kernel(
    const short* __restrict__ Q, const short* __restrict__ K,
    const short* __restrict__ VT, short* __restrict__ AO)
{
    __shared__ short Ksh[64*72];   // [key][d]
    __shared__ short VTs[64*72];   // [d][key]

    const int t  = threadIdx.x;
    const int w  = t >> 6;
    const int l  = t & 63;
    const int g  = l >> 4;
    const int ln = l & 15;

    const int bh = blockIdx.y;
    const int q0 = blockIdx.x * 128;
    const short* Qb  = Q  + ((size_t)bh * LL + q0 + w*32) * HD;
    const short* Kb  = K  + (size_t)bh * LL * HD;
    const short* VTb = VT + (size_t)bh * HD * LL;

    // Q B-frags: [n=q=ln][k=d=8g+j(+32)]
    bf16x8 qb[2][2];
    #pragma unroll
    for (int qi = 0; qi < 2; ++qi) {
        qb[qi][0] = *(const bf16x8*)(Qb + (size_t)(qi*16 + ln)*HD + 8*g);
        qb[qi][1] = *(const bf16x8*)(Qb + (size_t)(qi*16 + ln)*HD + 32 + 8*g);
    }

    f32x4 O[2][4];                 // O[qi][db]: row q=4g+r, col d=db*16+ln
    #pragma unroll
    for (int qi = 0; qi < 2; ++qi)
        #pragma unroll
        for (int db = 0; db < 4; ++db) O[qi][db] = (f32x4){0.f,0.f,0.f,0.f};
    float l_acc[2] = {0.f, 0.f};

    const int sr = t >> 2;          // staging row (key for Ksh, d for VTs)
    const int sc = (t & 3) << 4;    // staging col chunk

    // prologue prefetch (kt = 0)
    bf16x8 k0r = *(const bf16x8*)(Kb  + (size_t)sr*HD + sc);
    bf16x8 k1r = *(const bf16x8*)(Kb  + (size_t)sr*HD + sc + 8);
    bf16x8 v0r = *(const bf16x8*)(VTb + (size_t)sr*LL + sc);
    bf16x8 v1r = *(const bf16x8*)(VTb + (size_t)sr*LL + sc + 8);

    for (int kt = 0; kt < LL; kt += 64) {
        __syncthreads();           // previous tile fully consumed
        *(bf16x8*)(Ksh + sr*72 + sc)     = k0r;
        *(bf16x8*)(Ksh + sr*72 + sc + 8) = k1r;
        *(bf16x8*)(VTs + sr*72 + sc)     = v0r;
        *(bf16x8*)(VTs + sr*72 + sc + 8) = v1r;
        __syncthreads();

        // prefetch next tile (branchless wrap)
        int kn = (kt + 64) & (LL - 1);
        k0r = *(const bf16x8*)(Kb  + (size_t)(kn + sr)*HD + sc);
        k1r = *(const bf16x8*)(Kb  + (size_t)(kn + sr)*HD + sc + 8);
        v0r = *(const bf16x8*)(VTb + (size_t)sr*LL + kn + sc);
        v1r = *(const bf16x8*)(VTb + (size_t)sr*LL + kn + sc + 8);

        uint2 pf[2][4];
        #pragma unroll
        for (int kb = 0; kb < 4; ++kb) {
            // K A-frags: [m=key=kb*16+ln][k=d]
            bf16x8 ka0 = *(const bf16x8*)(Ksh + (kb*16 + ln)*72 + 8*g);
            bf16x8 ka1 = *(const bf16x8*)(Ksh + (kb*16 + ln)*72 + 32 + 8*g);
            #pragma unroll
            for (int qi = 0; qi < 2; ++qi) {
                f32x4 S = (f32x4){0.f,0.f,0.f,0.f};
                S = __builtin_amdgcn_mfma_f32_16x16x32_bf16(ka0, qb[qi][0], S, 0, 0, 0);
                S = __builtin_amdgcn_mfma_f32_16x16x32_bf16(ka1, qb[qi][1], S, 0, 0, 0);
                float p0 = exp2x(S[0]), p1 = exp2x(S[1]);
                float p2 = exp2x(S[2]), p3 = exp2x(S[3]);
                l_acc[qi] += (p0 + p1) + (p2 + p3);
                pf[qi][kb].x = pk_bf16(p0, p1);
                pf[qi][kb].y = pk_bf16(p2, p3);
            }
        }

        // PV via 16x16x16: A = P (in regs, C-layout == A-layout), B = V from VTs
        #pragma unroll
        for (int kb = 0; kb < 4; ++kb) {
            bf16x4 pa0 = __builtin_bit_cast(bf16x4, pf[0][kb]);
            bf16x4 pa1 = __builtin_bit_cast(bf16x4, pf[1][kb]);
            #pragma unroll
            for (int db = 0; db < 4; ++db) {
                bf16x4 vf = *(const bf16x4*)(VTs + (db*16 + ln)*72 + kb*16 + 4*g);
                O[0][db] = mfma16x16x16_bf16(pa0, vf, O[0][db]);
                O[1][db] = mfma16x16x16_bf16(pa1, vf, O[1][db]);
            }
        }
    }

    // epilogue: l = sum over g-groups; O rows need l[q=4g+r] via shfl
    const int b = bh >> 4, h = bh & 15;
    #pragma unroll
    for (int qi = 0; qi < 2; ++qi) {
        float lr = l_acc[qi];
        lr += __shfl_xor(lr, 16);
        lr += __shfl_xor(lr, 32);      // every lane: l for q = ln
        #pragma unroll
        for (int r = 0; r < 4; ++r) {
            float inv = 1.0f / __shfl(lr, 4*g + r);
            int q = q0 + w*32 + qi*16 + 4*g + r;
            size_t base = ((size_t)(b*LL + q)) * DD + h*HD;
            #pragma unroll
            for (int db = 0; db < 4; ++db)
                AO[base + db*16 + ln] = f2bf(O[qi][db][r] * inv);
        }
    }
}

// ---------------------------------------------------------------------------
// Kernel 3: output projection, bf16 MFMA, fp32 out. grid (DD/128, BL/128).
// ---------------------------------------------------------------------------
__global__ __launch_bounds__(256) void oproj_mfma_kernel(
    const short* __restrict__ A, const short* __restrict__ Wob,
    float* __restrict__ out)
{
    __shared__ short Ash[128*64];
    __shared__ short Bsh[128*64];

    const int i0 = blockIdx.y * 128;
    const int n0 = blockIdx.x * 128;

    f32x4 acc[4][4];
    #pragma unroll
    for (int mi = 0; mi < 4; ++mi)
        #pragma unroll
        for (int nj = 0; nj < 4; ++nj) acc[mi][nj] = (f32x4){0.f,0.f,0.f,0.f};

    gemm_bt_128(A, Wob, Ash, Bsh, i0, n0, acc);

    const int t  = threadIdx.x;
    const int w  = t >> 6;
    const int g  = (t >> 4) & 3;
    const int ln = t & 15;
    const int rh = (w >> 1) * 64;
    const int ch = (w & 1) * 64;

    #pragma unroll
    for (int mi = 0; mi < 4; ++mi)
        #pragma unroll
        for (int r = 0; r < 4; ++r) {
            size_t base = (size_t)(i0 + rh + mi*16 + 4*g + r) * DD + n0 + ch;
            #pragma unroll
            for (int nj = 0; nj < 4; ++nj)
                out[base + nj*16 + ln] = acc[mi][nj][r];
        }
}

// ---------------------------------------------------------------------------
extern "C" void kernel_launch(void* const* d_in, const int* in_sizes, int n_in,
                              void* d_out, int out_size, void* d_ws, size_t ws_size,
                              hipStream_t stream) {
    const float* x  = (const float*)d_in[0];
    const float* Wq = (const float*)d_in[1];
    const float* Wk = (const float*)d_in[2];
    const float* Wv = (const float*)d_in[3];
    const float* Wo = (const float*)d_in[4];
    float* out = (float*)d_out;

    const size_t n_x = (size_t)BL * DD;   // 8.4M
    const size_t n_w = (size_t)DD * DD;   // 1.05M
    short* xb  = (short*)d_ws;
    short* Wqb = xb  + n_x;
    short* Wkb = Wqb + n_w;
    short* Wvb = Wkb + n_w;
    short* Wob = Wvb + n_w;
    short* Q   = Wob + n_w;
    short* K   = Q   + n_x;
    short* VTg = K   + n_x;               // V transposed: (B,H,Hd,L)
    short* AOb = VTg + n_x;
    float2* tab = (float2*)(AOb + n_x);   // 65536 float2 = 512 KB

    rope_tab_kernel<<<256, 256, 0, stream>>>(tab);
    cast_kernel<<<n_x/2048, 256, 0, stream>>>(x,  xb,  (int)n_x);
    cast_kernel<<<n_w/2048, 256, 0, stream>>>(Wq, Wqb, (int)n_w);
    cast_kernel<<<n_w/2048, 256, 0, stream>>>(Wk, Wkb, (int)n_w);
    cast_kernel<<<n_w/2048, 256, 0, stream>>>(Wv, Wvb, (int)n_w);
    cast_kernel<<<n_w/2048, 256, 0, stream>>>(Wo, Wob, (int)n_w);

    dim3 g1(DD/128, BL/128, 3);
    qkv_mfma_kernel<<<g1, 256, 0, stream>>>(xb, Wqb, Wkb, Wvb, tab, Q, K, VTg);

    dim3 g2(LL/128, BB*HH);
    attn_kernel<<<g2, 256, 0, stream>>>(Q, K, VTg, AOb);

    dim3 g3(DD/128, BL/128);
    oproj_mfma_kernel<<<g3, 256, 0, stream>>>(AOb, Wob, out);
}

// Round 7
// 291.220 us; speedup vs baseline: 1.0989x; 1.0989x over previous
//
#include <hip/hip_runtime.h>
#include <math.h>

#define BB 4
#define LL 2048
#define DD 1024
#define HH 16
#define HD 64
#define BL (BB*LL)

typedef __attribute__((ext_vector_type(8))) short bf16x8;
typedef __attribute__((ext_vector_type(4))) short bf16x4;
typedef __attribute__((ext_vector_type(4))) float f32x4;

__device__ inline short f2bf(float f) {
    union { float f; unsigned u; } v; v.f = f;
    unsigned r = v.u + 0x7fffu + ((v.u >> 16) & 1u);   // RNE
    return (short)(r >> 16);
}

// pack two fp32 -> two bf16 (truncation; p>=0 so bias is benign, ~2^-9 rel)
__device__ inline unsigned pk_bf16(float a, float b) {
    union { float f; unsigned u; } x, y; x.f = a; y.f = b;
    return (x.u >> 16) | (y.u & 0xffff0000u);
}

__device__ inline float exp2x(float x) {
#if __has_builtin(__builtin_amdgcn_exp2f)
    return __builtin_amdgcn_exp2f(x);
#else
    return exp2f(x);
#endif
}

__device__ inline f32x4 mfma16x16x16_bf16(bf16x4 a, bf16x4 b, f32x4 c) {
#if __has_builtin(__builtin_amdgcn_mfma_f32_16x16x16bf16_1k)
    return __builtin_amdgcn_mfma_f32_16x16x16bf16_1k(a, b, c, 0, 0, 0);
#elif __has_builtin(__builtin_amdgcn_mfma_f32_16x16x16_bf16)
    return __builtin_amdgcn_mfma_f32_16x16x16_bf16(a, b, c, 0, 0, 0);
#else
    f32x4 d;
    asm volatile("v_mfma_f32_16x16x16_bf16 %0, %1, %2, %3"
                 : "=v"(d) : "v"(a), "v"(b), "v"(c));
    return d;
#endif
}

__device__ inline void gload_lds16(const void* g, void* l) {
    __builtin_amdgcn_global_load_lds(
        (const __attribute__((address_space(1))) unsigned int*)g,
        (__attribute__((address_space(3))) unsigned int*)l, 16, 0, 0);
}

// ---------------------------------------------------------------------------
// fp32 -> bf16 cast, 8 elem/thread.
// ---------------------------------------------------------------------------
__global__ __launch_bounds__(256) void cast_kernel(
    const float* __restrict__ in, short* __restrict__ out, int n)
{
    int i = (blockIdx.x * 256 + threadIdx.x) * 8;
    float4 a = *(const float4*)(in + i);
    float4 b = *(const float4*)(in + i + 4);
    bf16x8 o;
    o[0]=f2bf(a.x); o[1]=f2bf(a.y); o[2]=f2bf(a.z); o[3]=f2bf(a.w);
    o[4]=f2bf(b.x); o[5]=f2bf(b.y); o[6]=f2bf(b.z); o[7]=f2bf(b.w);
    *(bf16x8*)(out + i) = o;
}

// 4 weight matrices (contiguous dsts), one launch. grid = 4 * n_w/2048.
__global__ __launch_bounds__(256) void cast4_kernel(
    const float* __restrict__ w0, const float* __restrict__ w1,
    const float* __restrict__ w2, const float* __restrict__ w3,
    short* __restrict__ out)
{
    const int nw_blocks = (DD*DD) / 2048;
    int sel = blockIdx.x / nw_blocks;
    int blk = blockIdx.x % nw_blocks;
    const float* in = (sel == 0) ? w0 : (sel == 1) ? w1 : (sel == 2) ? w2 : w3;
    int i = (blk * 256 + threadIdx.x) * 8;
    float4 a = *(const float4*)(in + i);
    float4 b = *(const float4*)(in + i + 4);
    bf16x8 o;
    o[0]=f2bf(a.x); o[1]=f2bf(a.y); o[2]=f2bf(a.z); o[3]=f2bf(a.w);
    o[4]=f2bf(b.x); o[5]=f2bf(b.y); o[6]=f2bf(b.z); o[7]=f2bf(b.w);
    *(bf16x8*)(out + (size_t)sel * DD * DD + i) = o;
}

// ---------------------------------------------------------------------------
// RoPE table: tab[l*32 + f] = (cos, sin) of l * 10000^(-f/32), f=0..31.
// ---------------------------------------------------------------------------
__global__ __launch_bounds__(256) void rope_tab_kernel(float2* __restrict__ tab)
{
    int idx = blockIdx.x * 256 + threadIdx.x;
    int lq = idx >> 5, f = idx & 31;
    float inv = __expf((float)f * (-9.210340371976184f / 32.0f));
    float s, c;
    sincosf((float)lq * inv, &s, &c);
    tab[idx] = make_float2(c, s);
}

// ---------------------------------------------------------------------------
// Shared 128x128-tile bf16 MFMA K-loop (m97 structure: global_load_lds w=16,
// unpadded LDS, 2-barrier). R6's reg-staging variant reverted: it raised
// VGPR with no gain.
// ---------------------------------------------------------------------------
__device__ inline void gemm_bt_128(const short* __restrict__ A,
                                   const short* __restrict__ B,
                                   short* Ash, short* Bsh,
                                   int i0, int n0, f32x4 (&acc)[4][4])
{
    const int t  = threadIdx.x;
    const int w  = t >> 6;
    const int l  = t & 63;
    const int g  = (t >> 4) & 3;
    const int ln = t & 15;
    const int rh = (w >> 1) * 64;
    const int ch = (w & 1) * 64;
    const int srow = w * 8 + (l >> 3);
    const int skol = (l & 7) * 8;

    for (int k0 = 0; k0 < DD; k0 += 64) {
        __syncthreads();
        const short* ga = A + (size_t)(i0 + srow) * DD + k0 + skol;
        const short* gb = B + (size_t)(n0 + srow) * DD + k0 + skol;
        short* la = Ash + w * 512;   // wave-uniform base
        short* lb = Bsh + w * 512;
        #pragma unroll
        for (int j = 0; j < 4; ++j) {
            gload_lds16(ga + j * 32 * DD, la + j * 2048);
            gload_lds16(gb + j * 32 * DD, lb + j * 2048);
        }
        __syncthreads();

        #pragma unroll
        for (int kk = 0; kk < 2; ++kk) {
            bf16x8 af[4], bfr[4];
            #pragma unroll
            for (int mi = 0; mi < 4; ++mi)
                af[mi] = *(const bf16x8*)(Ash + (rh + mi*16 + ln)*64 + kk*32 + 8*g);
            #pragma unroll
            for (int nj = 0; nj < 4; ++nj)
                bfr[nj] = *(const bf16x8*)(Bsh + (ch + nj*16 + ln)*64 + kk*32 + 8*g);
            #pragma unroll
            for (int mi = 0; mi < 4; ++mi)
                #pragma unroll
                for (int nj = 0; nj < 4; ++nj)
                    acc[mi][nj] = __builtin_amdgcn_mfma_f32_16x16x32_bf16(
                        af[mi], bfr[nj], acc[mi][nj], 0, 0, 0);
        }
    }
}

// ---------------------------------------------------------------------------
// Kernel 1: QKV projection + RoPE. 1-D grid 1536, XCD-aware decode:
// xcd r = gid&7 owns i-tiles r*8..r*8+7 (2 MB of x stays in that XCD's L2)
// and iterates all 24 (n,z) W-tiles (W-tile reused back-to-back).
// z=0/1: Q/K roped via table, Q scaled 0.125*log2(e), layout (B,H,L,Hd).
// z=2: V transposed (B,H,Hd,L) via two-pass LDS transpose.
// ---------------------------------------------------------------------------
__global__ __launch_bounds__(256) void qkv_mfma_kernel(
    const short* __restrict__ xb, const short* __restrict__ Wqb,
    const short* __restrict__ Wkb, const short* __restrict__ Wvb,
    const float2* __restrict__ rope_tab,
    short* __restrict__ Qo, short* __restrict__ Ko, short* __restrict__ Vo)
{
    __shared__ short Ash[128*64];
    __shared__ short Bsh[128*64];

    const int gid = blockIdx.x;
    const int r8  = gid & 7;           // XCD slot (round-robin heuristic)
    const int u   = gid >> 3;          // 0..191
    const int i_idx = r8 * 8 + (u & 7);      // 0..63
    const int nz  = u >> 3;                  // 0..23
    const int n_idx = nz & 7;                // 0..7
    const int z   = nz >> 3;                 // 0..2

    const short* Wm = (z == 0) ? Wqb : ((z == 1) ? Wkb : Wvb);
    const int i0 = i_idx * 128;
    const int n0 = n_idx * 128;

    f32x4 acc[4][4];
    #pragma unroll
    for (int mi = 0; mi < 4; ++mi)
        #pragma unroll
        for (int nj = 0; nj < 4; ++nj) acc[mi][nj] = (f32x4){0.f,0.f,0.f,0.f};

    gemm_bt_128(xb, Wm, Ash, Bsh, i0, n0, acc);

    const int t  = threadIdx.x;
    const int w  = t >> 6;
    const int g  = (t >> 4) & 3;
    const int ln = t & 15;
    const int rh = (w >> 1) * 64;

    if (z == 2) {
        // two passes over heads; buf[64 d][136 seq-stride] spans Ash..Bsh.
        short* buf = Ash;
        const int b = i0 >> 11, l0 = i0 & (LL - 1);
        const int d = t >> 2;
        const int c = t & 3;
        #pragma unroll
        for (int hp = 0; hp < 2; ++hp) {
            __syncthreads();
            if ((w & 1) == hp) {
                #pragma unroll
                for (int nj = 0; nj < 4; ++nj)
                    #pragma unroll
                    for (int mi = 0; mi < 4; ++mi)
                        #pragma unroll
                        for (int r = 0; r < 4; ++r)
                            buf[(nj*16 + ln)*136 + rh + mi*16 + 4*g + r]
                                = f2bf(acc[mi][nj][r]);
            }
            __syncthreads();
            short* dst = Vo + ((size_t)((b*HH + n_idx*2 + hp)*HD + d)) * LL + l0;
            #pragma unroll
            for (int j = 0; j < 4; ++j)
                *(bf16x8*)(dst + c*8 + j*32) =
                    *(const bf16x8*)(buf + d*136 + c*8 + j*32);
        }
    } else {
        const int h = n_idx * 2 + (w & 1);
        short* Om = (z == 0) ? Qo : Ko;
        // Q: 1/sqrt(64) * log2(e) so scores feed exp2 directly
        const float sc = (z == 0) ? 0.180336880111112f : 1.0f;
        #pragma unroll
        for (int mi = 0; mi < 4; ++mi)
            #pragma unroll
            for (int r = 0; r < 4; ++r) {
                int i = i0 + rh + mi*16 + 4*g + r;
                int b = i >> 11, lq = i & (LL - 1);
                float2 cs0 = rope_tab[lq*32 + ln];        // freq ln
                float2 cs1 = rope_tab[lq*32 + ln + 16];   // freq ln+16
                float r0 = (acc[mi][0][r]*cs0.x - acc[mi][2][r]*cs0.y) * sc;
                float r2 = (acc[mi][2][r]*cs0.x + acc[mi][0][r]*cs0.y) * sc;
                float r1 = (acc[mi][1][r]*cs1.x - acc[mi][3][r]*cs1.y) * sc;
                float r3 = (acc[mi][3][r]*cs1.x + acc[mi][1][r]*cs1.y) * sc;
                size_t base = ((size_t)(b*HH + h) * LL + lq) * HD;
                Om[base + ln     ] = f2bf(r0);
                Om[base + ln + 16] = f2bf(r1);
                Om[base + ln + 32] = f2bf(r2);
                Om[base + ln + 48] = f2bf(r3);
            }
    }
}

// ---------------------------------------------------------------------------
// Kernel 2: bf16 MFMA flash attention (R5 loop structure restored).
// grid = (B*H, L/128): bh on x => the 16 q-tile blocks sharing one bh get
// gid = qt*64 + bh == bh (mod 8) -> same XCD -> K/V stay in one L2.
// ---------------------------------------------------------------------------
__global__ __launch_bounds__(256) void attn_kernel(
    const short* __restrict__ Q, const short* __restrict__ K,
    const short* __restrict__ VT, short* __restrict__ AO)
{
    __shared__ short Ksh[64*72];   // [key][d]
    __shared__ short VTs[64*72];   // [d][key]

    const int t  = threadIdx.x;
    const int w  = t >> 6;
    const int l  = t & 63;
    const int g  = l >> 4;
    const int ln = l & 15;

    const int bh = blockIdx.x;
    const int q0 = blockIdx.y * 128;
    const short* Qb  = Q  + ((size_t)bh * LL + q0 + w*32) * HD;
    const short* Kb  = K  + (size_t)bh * LL * HD;
    const short* VTb = VT + (size_t)bh * HD * LL;

    // Q B-frags: [n=q=ln][k=d=8g+j(+32)]
    bf16x8 qb[2][2];
    #pragma unroll
    for (int qi = 0; qi < 2; ++qi) {
        qb[qi][0] = *(const bf16x8*)(Qb + (size_t)(qi*16 + ln)*HD + 8*g);
        qb[qi][1] = *(const bf16x8*)(Qb + (size_t)(qi*16 + ln)*HD + 32 + 8*g);
    }

    f32x4 O[2][4];                 // O[qi][db]: row q=4g+r, col d=db*16+ln
    #pragma unroll
    for (int qi = 0; qi < 2; ++qi)
        #pragma unroll
        for (int db = 0; db < 4; ++db) O[qi][db] = (f32x4){0.f,0.f,0.f,0.f};
    float l_acc[2] = {0.f, 0.f};

    const int sr = t >> 2;          // staging row (key for Ksh, d for VTs)
    const int sc = (t & 3) << 4;    // staging col chunk

    for (int kt = 0; kt < LL; kt += 64) {
        bf16x8 k0 = *(const bf16x8*)(Kb  + (size_t)(kt + sr)*HD + sc);
        bf16x8 k1 = *(const bf16x8*)(Kb  + (size_t)(kt + sr)*HD + sc + 8);
        bf16x8 v0 = *(const bf16x8*)(VTb + (size_t)sr*LL + kt + sc);
        bf16x8 v1 = *(const bf16x8*)(VTb + (size_t)sr*LL + kt + sc + 8);
        __syncthreads();           // previous tile fully consumed
        *(bf16x8*)(Ksh + sr*72 + sc)     = k0;
        *(bf16x8*)(Ksh + sr*72 + sc + 8) = k1;
        *(bf16x8*)(VTs + sr*72 + sc)     = v0;
        *(bf16x8*)(VTs + sr*72 + sc + 8) = v1;
        __syncthreads();

        uint2 pf[2][4];
        #pragma unroll
        for (int kb = 0; kb < 4; ++kb) {
            // K A-frags: [m=key=kb*16+ln][k=d]
            bf16x8 ka0 = *(const bf16x8*)(Ksh + (kb*16 + ln)*72 + 8*g);
            bf16x8 ka1 = *(const bf16x8*)(Ksh + (kb*16 + ln)*72 + 32 + 8*g);
            #pragma unroll
            for (int qi = 0; qi < 2; ++qi) {
                f32x4 S = (f32x4){0.f,0.f,0.f,0.f};
                S = __builtin_amdgcn_mfma_f32_16x16x32_bf16(ka0, qb[qi][0], S, 0, 0, 0);
                S = __builtin_amdgcn_mfma_f32_16x16x32_bf16(ka1, qb[qi][1], S, 0, 0, 0);
                float p0 = exp2x(S[0]), p1 = exp2x(S[1]);
                float p2 = exp2x(S[2]), p3 = exp2x(S[3]);
                l_acc[qi] += (p0 + p1) + (p2 + p3);
                pf[qi][kb].x = pk_bf16(p0, p1);
                pf[qi][kb].y = pk_bf16(p2, p3);
            }
        }

        // PV via 16x16x16: A = P (in regs, C-layout == A-layout), B = V from VTs
        #pragma unroll
        for (int kb = 0; kb < 4; ++kb) {
            bf16x4 pa0 = __builtin_bit_cast(bf16x4, pf[0][kb]);
            bf16x4 pa1 = __builtin_bit_cast(bf16x4, pf[1][kb]);
            #pragma unroll
            for (int db = 0; db < 4; ++db) {
                bf16x4 vf = *(const bf16x4*)(VTs + (db*16 + ln)*72 + kb*16 + 4*g);
                O[0][db] = mfma16x16x16_bf16(pa0, vf, O[0][db]);
                O[1][db] = mfma16x16x16_bf16(pa1, vf, O[1][db]);
            }
        }
    }

    // epilogue: l = sum over g-groups; O rows need l[q=4g+r] via shfl
    const int b = bh >> 4, h = bh & 15;
    #pragma unroll
    for (int qi = 0; qi < 2; ++qi) {
        float lr = l_acc[qi];
        lr += __shfl_xor(lr, 16);
        lr += __shfl_xor(lr, 32);      // every lane: l for q = ln
        #pragma unroll
        for (int r = 0; r < 4; ++r) {
            float inv = 1.0f / __shfl(lr, 4*g + r);
            int q = q0 + w*32 + qi*16 + 4*g + r;
            size_t base = ((size_t)(b*LL + q)) * DD + h*HD;
            #pragma unroll
            for (int db = 0; db < 4; ++db)
                AO[base + db*16 + ln] = f2bf(O[qi][db][r] * inv);
        }
    }
}

// ---------------------------------------------------------------------------
// Kernel 3: output projection. 1-D grid 512, same XCD-aware decode as qkv:
// each XCD owns 8 i-tiles of A + iterates the 8 Wo n-tiles.
// ---------------------------------------------------------------------------
__global__ __launch_bounds__(256) void oproj_mfma_kernel(
    const short* __restrict__ A, const short* __restrict__ Wob,
    float* __restrict__ out)
{
    __shared__ short Ash[128*64];
    __shared__ short Bsh[128*64];

    const int gid = blockIdx.x;
    const int r8  = gid & 7;
    const int u   = gid >> 3;              // 0..63
    const int i_idx = r8 * 8 + (u & 7);    // 0..63
    const int n_idx = u >> 3;              // 0..7
    const int i0 = i_idx * 128;
    const int n0 = n_idx * 128;

    f32x4 acc[4][4];
    #pragma unroll
    for (int mi = 0; mi < 4; ++mi)
        #pragma unroll
        for (int nj = 0; nj < 4; ++nj) acc[mi][nj] = (f32x4){0.f,0.f,0.f,0.f};

    gemm_bt_128(A, Wob, Ash, Bsh, i0, n0, acc);

    const int t  = threadIdx.x;
    const int w  = t >> 6;
    const int g  = (t >> 4) & 3;
    const int ln = t & 15;
    const int rh = (w >> 1) * 64;
    const int ch = (w & 1) * 64;

    #pragma unroll
    for (int mi = 0; mi < 4; ++mi)
        #pragma unroll
        for (int r = 0; r < 4; ++r) {
            size_t base = (size_t)(i0 + rh + mi*16 + 4*g + r) * DD + n0 + ch;
            #pragma unroll
            for (int nj = 0; nj < 4; ++nj)
                out[base + nj*16 + ln] = acc[mi][nj][r];
        }
}

// ---------------------------------------------------------------------------
extern "C" void kernel_launch(void* const* d_in, const int* in_sizes, int n_in,
                              void* d_out, int out_size, void* d_ws, size_t ws_size,
                              hipStream_t stream) {
    const float* x  = (const float*)d_in[0];
    const float* Wq = (const float*)d_in[1];
    const float* Wk = (const float*)d_in[2];
    const float* Wv = (const float*)d_in[3];
    const float* Wo = (const float*)d_in[4];
    float* out = (float*)d_out;

    const size_t n_x = (size_t)BL * DD;   // 8.4M
    const size_t n_w = (size_t)DD * DD;   // 1.05M
    short* xb  = (short*)d_ws;
    short* Wqb = xb  + n_x;               // Wqb..Wob contiguous (cast4 relies on it)
    short* Wkb = Wqb + n_w;
    short* Wvb = Wkb + n_w;
    short* Wob = Wvb + n_w;
    short* Q   = Wob + n_w;
    short* K   = Q   + n_x;
    short* VTg = K   + n_x;               // V transposed: (B,H,Hd,L)
    short* AOb = VTg + n_x;
    float2* tab = (float2*)(AOb + n_x);   // 65536 float2 = 512 KB

    rope_tab_kernel<<<256, 256, 0, stream>>>(tab);
    cast_kernel<<<n_x/2048, 256, 0, stream>>>(x, xb, (int)n_x);
    cast4_kernel<<<4*(n_w/2048), 256, 0, stream>>>(Wq, Wk, Wv, Wo, Wqb);

    qkv_mfma_kernel<<<1536, 256, 0, stream>>>(xb, Wqb, Wkb, Wvb, tab, Q, K, VTg);

    dim3 g2(BB*HH, LL/128);
    attn_kernel<<<g2, 256, 0, stream>>>(Q, K, VTg, AOb);

    oproj_mfma_kernel<<<512, 256, 0, stream>>>(AOb, Wob, out);
}